// Round 19
// baseline (271.610 us; speedup 1.0000x reference)
//
#include <hip/hip_runtime.h>

#define DEV __device__ __forceinline__

typedef __attribute__((ext_vector_type(4))) float f32x4;
typedef __attribute__((ext_vector_type(8))) short short8;
typedef __attribute__((ext_vector_type(4))) short s16x4;
typedef __attribute__((ext_vector_type(4))) float f32x4v;

DEV short f2bf(float f) {
  union { float f; unsigned u; } v; v.f = f;
  unsigned r = (v.u + 0x7FFFu + ((v.u >> 16) & 1u)) >> 16;
  return (short)r;
}

DEV void gload16(const void* g, void* l) {
  __builtin_amdgcn_global_load_lds(
      (const __attribute__((address_space(1))) void*)g,
      (__attribute__((address_space(3))) void*)l, 16, 0, 0);
}

#define BAR() __builtin_amdgcn_s_barrier()
#define LGKMW(n)                                              \
  {                                                           \
    asm volatile("s_waitcnt lgkmcnt(" #n ")" ::: "memory");   \
    __builtin_amdgcn_sched_barrier(0);                        \
  }
#define VMW(n)                                                \
  {                                                           \
    asm volatile("s_waitcnt vmcnt(" #n ")" ::: "memory");     \
    __builtin_amdgcn_sched_barrier(0);                        \
  }

// ---------------- merged prep kernel (unchanged from R14/R16) ----------------
//   blocks [0,256):    wkt4  | [256,512): w2f | [512,8704): keys

__global__ __launch_bounds__(256) void k_prep_all(
    const float* __restrict__ keys, const float* __restrict__ w2,
    const float* __restrict__ w1, const float* __restrict__ query,
    const float* __restrict__ b1, short* __restrict__ keysb,
    short* __restrict__ w2f, short* __restrict__ wktf,
    float* __restrict__ biasb) {
  __shared__ __align__(16) char smem[45056];
  const int bid = blockIdx.x;
  const int tid = threadIdx.x;

  if (bid < 256) {
    short (*tile)[64][72] = (short (*)[64][72])(smem);
    float (*qlds)[256] = (float (*)[256])(smem + 36864);
    float (*redm)[64][4] = (float (*)[64][4])(smem + 40960);
    const int r = bid;
    const int bg = r & 15, d0g = r >> 4, d0 = d0g * 64;
    const int d = tid & 63, mq = tid >> 6;

    for (int idx = tid; idx < 1024; idx += 256)
      qlds[idx >> 8][idx & 255] = query[(bg * 4 + (idx >> 8)) * 256 + (idx & 255)];
    __syncthreads();

    float bacc[4] = {0.f, 0.f, 0.f, 0.f};
    const int l = tid & 63, cgl = tid >> 6;

    for (int mc = 0; mc < 4; ++mc) {
#pragma unroll 4
      for (int i = 0; i < 16; ++i) {
        int ml = i * 4 + mq;
        int m = mc * 64 + ml;
        float wa = w1[(size_t)m * 1024 + d0 + d];
        float wb = w1[(size_t)(256 + m) * 1024 + d0 + d];
        float wc = w1[(size_t)(512 + m) * 1024 + d0 + d];
        float wd = w1[(size_t)(768 + m) * 1024 + d0 + d];
        float bc = wb - wc, ac = wa + wc;
#pragma unroll
        for (int bb = 0; bb < 4; ++bb) {
          float qv = qlds[bb][m];
          tile[bb][d][ml] = f2bf(bc + qv * wd);
          bacc[bb] += qv * ac;
        }
      }
      __syncthreads();
#pragma unroll
      for (int bb = 0; bb < 4; ++bb) {
        short* ob = wktf + (size_t)(bg * 4 + bb) * 262144;
#pragma unroll
        for (int kh = 0; kh < 2; ++kh) {
          short8 v = *(const short8*)&tile[bb][cgl * 16 + (l & 15)]
                                          [kh * 32 + (l >> 4) * 8];
          *(short8*)&ob[((size_t)((mc * 2 + kh) * 64 + d0g * 4 + cgl)) * 512 + l * 8] = v;
        }
      }
      __syncthreads();
    }

    redm[0][d][mq] = bacc[0];
    redm[1][d][mq] = bacc[1];
    redm[2][d][mq] = bacc[2];
    redm[3][d][mq] = bacc[3];
    __syncthreads();
    const int bb = tid >> 6, dd = tid & 63;
    biasb[(bg * 4 + bb) * 1024 + d0 + dd] =
        redm[bb][dd][0] + redm[bb][dd][1] + redm[bb][dd][2] + redm[bb][dd][3] +
        b1[d0 + dd];
  } else if (bid < 512) {
    float (*tile)[65] = (float (*)[65])(smem);
    const int r = bid - 256;
    const int kt = r & 15, n0 = (r >> 4) * 64;
    const int a = tid & 63, q = tid >> 6;
#pragma unroll
    for (int i = 0; i < 16; ++i) {
      int kk = i * 4 + q;
      tile[kk][a] = w2[(size_t)(kt * 64 + kk) * 1024 + n0 + a];
    }
    __syncthreads();
    const int l = tid & 63, cgl = tid >> 6;
#pragma unroll
    for (int kh = 0; kh < 2; ++kh) {
      short8 v;
#pragma unroll
      for (int j = 0; j < 8; ++j)
        v[j] = f2bf(tile[kh * 32 + (l >> 4) * 8 + j][cgl * 16 + (l & 15)]);
      *(short8*)&w2f[((size_t)((kt * 2 + kh) * 64 + (n0 >> 4) + cgl)) * 512 + l * 8] = v;
    }
  } else {
    int i = ((bid - 512) * 256 + tid) * 8;
    f32x4v v0 = *(const f32x4v*)(keys + i);
    f32x4v v1 = *(const f32x4v*)(keys + i + 4);
    short8 s;
    s[0] = f2bf(v0[0]); s[1] = f2bf(v0[1]); s[2] = f2bf(v0[2]); s[3] = f2bf(v0[3]);
    s[4] = f2bf(v1[0]); s[5] = f2bf(v1[1]); s[6] = f2bf(v1[2]); s[7] = f2bf(v1[3]);
    *(short8*)(keysb + i) = s;
  }
}

// ---------------- iso-traffic high-TLP GEMM (TN), 16x16x32 ------------------
// BM=128, BN=256, BK=64 — SAME block footprint/traffic as the R8 baseline —
// but 512 thr = 8 waves of 64x64 wave-tiles (wr=wid>>2 rows, wcc=wid&3 cols).
// acc 64 + bf[4][2] 32 + af[4] 16 ~= 112+addr VGPR -> launch_bounds(512,4)
// caps at 128 VGPR -> 2 blocks/CU = 16 waves/CU = 4 waves/SIMD (2x R8's TLP).
// LDS: 4 x 16KB A-buffers. B single-banked, loaded ONE tile ahead: each kh
// bank refilled immediately after its last MFMA use (reg-WAR safe in-order;
// compiler RAW vmcnt protects consumption). End-of-phase VMW(10) =
// LOADB(t+1,kh1)[4]+STAGE(t+2)[2]+LOADB(t+1,kh0)[4]; drains STAGE(t+1).
// MODE 1: per-batch keys@Wk + bias, relu -> h1 (bf16).  K=256 (KT=4).
// MODE 2: h1@w2f + b2, relu, dot w_score -> score partials. K=1024 (KT=16).

template <int MODE>
__global__ __launch_bounds__(512, 4) void k_gemm(const short* __restrict__ A,
                                                 const short* __restrict__ Bf,
                                                 const float* __restrict__ bias,
                                                 const float* __restrict__ wscore,
                                                 short* __restrict__ hout,
                                                 float* __restrict__ spart) {
  __shared__ short lds[32768];  // 4 bufs x 8192 shorts (16KB each)
  constexpr int SK = (MODE == 1) ? 256 : 1024;
  constexpr int KT = (MODE == 1) ? 4 : 16;

  const int tid = threadIdx.x;
  const int bx = blockIdx.x;
  const int L = (bx & 7) * 256 + (bx >> 3);  // XCD swizzle (2048%8==0)

  const short *Ab, *Bb;
  const float *biasp, *wsp = nullptr;
  short* houtp = nullptr;
  int rt, ct;
  if constexpr (MODE == 1) {
    const int b = L >> 5;
    rt = (L >> 2) & 7; ct = L & 3;
    Ab = A + ((size_t)(b * 1024 + rt * 128)) * 256;
    Bb = Bf + (size_t)b * 262144;
    biasp = bias + b * 1024 + ct * 256;
    houtp = hout + ((size_t)(b * 1024 + rt * 128)) * 1024 + ct * 256;
  } else {
    rt = L >> 2; ct = L & 3;
    Ab = A + (size_t)rt * 128 * 1024;
    Bb = Bf;
    biasp = bias + ct * 256;
    wsp = wscore + ct * 256;
  }

  // A staging (512 thr, 2 chunks each): chunk s -> row=s>>3, slot=s&7,
  // src k-chunk = slot^(row&7)
  int gA[2], dA[2];
#pragma unroll
  for (int j = 0; j < 2; ++j) {
    int s = tid + j * 512, row = s >> 3, kc = (s & 7) ^ (row & 7);
    gA[j] = row * SK + kc * 8;
    dA[j] = s * 8;
  }
  auto STAGE = [&](int kt) {
    const int bb = (kt & 3) * 8192;
#pragma unroll
    for (int j = 0; j < 2; ++j) gload16(Ab + gA[j] + kt * 64, &lds[bb + dA[j]]);
  };

  const int lane = tid & 63, l15 = lane & 15, l4 = lane >> 4;
  const int wid = tid >> 6, wr = wid >> 2, wcc = wid & 3;
  // af read: row = wr*64 + m*16 + l15; chunk kh*4+l4 stored at slot^(l15&7)
  const int afo0 = wr * 4096 + l15 * 64 + ((l4 ^ (l15 & 7)) * 8);
  const int afo1 = wr * 4096 + l15 * 64 + (((4 + l4) ^ (l15 & 7)) * 8);

  f32x4 acc[4][4];
#pragma unroll
  for (int m = 0; m < 4; ++m)
#pragma unroll
    for (int n = 0; n < 4; ++n) acc[m][n] = f32x4{0.f, 0.f, 0.f, 0.f};
  short8 bf[4][2];  // [n][kh], single-banked
  short8 af[4];

#define LOADB(kt, kh_)                                                          \
  _Pragma("unroll") for (int n_ = 0; n_ < 4; ++n_) {                            \
    bf[n_][kh_] = *(const short8*)(Bb +                                         \
        ((size_t)(((kt) * 2 + (kh_)) * 64 + ct * 16 + wcc * 4 + n_) << 9) +     \
        lane * 8);                                                              \
  }

  // prologue: STAGE(0)[2], LOADB(0,both)[8], STAGE(1)[2] -> VMW(10) drains
  // STAGE(0); bf RAW-protected by compiler waits.
  STAGE(0);
  LOADB(0, 0);
  LOADB(0, 1);
  STAGE(1);
  VMW(10);
  BAR();

#pragma unroll
  for (int t = 0; t < KT; ++t) {
    const int bb = (t & 3) * 8192;
    // kh0
#pragma unroll
    for (int m = 0; m < 4; ++m) af[m] = *(const short8*)&lds[bb + afo0 + m * 1024];
    LGKMW(0);
    __builtin_amdgcn_s_setprio(1);
#pragma unroll
    for (int m = 0; m < 4; ++m)
#pragma unroll
      for (int n = 0; n < 4; ++n)
        acc[m][n] = __builtin_amdgcn_mfma_f32_16x16x32_bf16(bf[n][0], af[m],
                                                            acc[m][n], 0, 0, 0);
    __builtin_amdgcn_s_setprio(0);
    if (t + 1 < KT) LOADB(t + 1, 0);   // refill kh0 bank (last use was above)
    // kh1
#pragma unroll
    for (int m = 0; m < 4; ++m) af[m] = *(const short8*)&lds[bb + afo1 + m * 1024];
    if (t + 2 < KT) STAGE(t + 2);
    LGKMW(0);
    __builtin_amdgcn_s_setprio(1);
#pragma unroll
    for (int m = 0; m < 4; ++m)
#pragma unroll
      for (int n = 0; n < 4; ++n)
        acc[m][n] = __builtin_amdgcn_mfma_f32_16x16x32_bf16(bf[n][1], af[m],
                                                            acc[m][n], 0, 0, 0);
    __builtin_amdgcn_s_setprio(0);
    if (t + 1 < KT) LOADB(t + 1, 1);   // refill kh1 bank
    if (t + 2 < KT) {
      VMW(10);       // keep LOADB(t+1)[8]+STAGE(t+2)[2]; drains STAGE(t+1)
    } else if (t + 1 < KT) {
      VMW(8);        // keep LOADB(t+1)[8]
    } else {
      VMW(0);        // final tile
    }
    BAR();
  }
#undef LOADB

  // ---------------- epilogue ----------------
  // C fragments: row = wr*64 + m*16 + l15, col(n,r2) = wcc*64 + n*16 + l4*4 + r2
  if constexpr (MODE == 1) {
    float bv[4][4];
#pragma unroll
    for (int n = 0; n < 4; ++n)
#pragma unroll
      for (int r2 = 0; r2 < 4; ++r2)
        bv[n][r2] = biasp[wcc * 64 + n * 16 + l4 * 4 + r2];
#pragma unroll
    for (int m = 0; m < 4; ++m) {
      int row = wr * 64 + m * 16 + l15;
#pragma unroll
      for (int n = 0; n < 4; ++n) {
        s16x4 pk;
#pragma unroll
        for (int r2 = 0; r2 < 4; ++r2)
          pk[r2] = f2bf(fmaxf(acc[m][n][r2] + bv[n][r2], 0.f));
        *(s16x4*)&houtp[(size_t)row * 1024 + wcc * 64 + n * 16 + l4 * 4] = pk;
      }
    }
  } else {
    float bv[4][4], wv[4][4];
#pragma unroll
    for (int n = 0; n < 4; ++n)
#pragma unroll
      for (int r2 = 0; r2 < 4; ++r2) {
        int c = wcc * 64 + n * 16 + l4 * 4 + r2;
        bv[n][r2] = biasp[c];
        wv[n][r2] = wsp[c];
      }
    float* so = spart + ((size_t)(ct * 4 + wcc) << 16) + rt * 128 + wr * 64;
#pragma unroll
    for (int m = 0; m < 4; ++m) {
      float s = 0.f;
#pragma unroll
      for (int n = 0; n < 4; ++n)
#pragma unroll
        for (int r2 = 0; r2 < 4; ++r2)
          s += fmaxf(acc[m][n][r2] + bv[n][r2], 0.f) * wv[n][r2];
      s += __shfl_xor(s, 16);
      s += __shfl_xor(s, 32);
      if (lane < 16) so[m * 16 + l15] = s;
    }
  }
}

// ---------------- fused softmax + output partials ----------------
__global__ __launch_bounds__(256) void k_out(const float* __restrict__ spart,
                                             const float* __restrict__ mask,
                                             const float* __restrict__ bscore,
                                             const float* __restrict__ values,
                                             float* __restrict__ part) {
  const int b = blockIdx.x >> 3, ts = blockIdx.x & 7;
  const int tid = threadIdx.x;
  __shared__ float sm[1024];
  __shared__ float red[8];
  const float bs = bscore[0];
  float lmax = -3.0e38f;
  for (int t = tid; t < 1024; t += 256) {
    float s = bs;
#pragma unroll
    for (int c = 0; c < 16; ++c) s += spart[(size_t)c * 65536 + b * 1024 + t];
    float lg = s + mask[b * 1024 + t] * (-1e9f);
    sm[t] = lg;
    lmax = fmaxf(lmax, lg);
  }
  for (int o = 32; o; o >>= 1) lmax = fmaxf(lmax, __shfl_xor(lmax, o));
  const int wid = tid >> 6, lane = tid & 63;
  if (lane == 0) red[wid] = lmax;
  __syncthreads();
  float bmax = fmaxf(fmaxf(red[0], red[1]), fmaxf(red[2], red[3]));
  float lsum = 0.f;
  for (int t = tid; t < 1024; t += 256) {
    float e = __expf(sm[t] - bmax);
    sm[t] = e;
    lsum += e;
  }
  for (int o = 32; o; o >>= 1) lsum += __shfl_xor(lsum, o);
  __syncthreads();
  if (lane == 0) red[wid] = lsum;
  __syncthreads();
  const float inv = 1.0f / (red[0] + red[1] + red[2] + red[3]);

  const float* vb = values + ((size_t)b * 1024 + ts * 128) * 1024 + tid * 4;
  f32x4 acc = {0.f, 0.f, 0.f, 0.f};
#pragma unroll 8
  for (int t = 0; t < 128; ++t) {
    f32x4v v = *(const f32x4v*)(vb + (size_t)t * 1024);
    float a = sm[ts * 128 + t] * inv;
    acc[0] += a * v[0]; acc[1] += a * v[1]; acc[2] += a * v[2]; acc[3] += a * v[3];
  }
  *(f32x4*)(part + ((size_t)(b * 8 + ts)) * 1024 + tid * 4) = acc;
}

__global__ __launch_bounds__(256) void k_red(const float* __restrict__ part,
                                             float* __restrict__ out) {
  const int b = blockIdx.x;
  const int c4 = threadIdx.x * 4;
  f32x4 s = {0.f, 0.f, 0.f, 0.f};
#pragma unroll
  for (int ts = 0; ts < 8; ++ts) {
    f32x4v v = *(const f32x4v*)(part + ((size_t)(b * 8 + ts)) * 1024 + c4);
    s[0] += v[0]; s[1] += v[1]; s[2] += v[2]; s[3] += v[3];
  }
  *(f32x4*)(out + b * 1024 + c4) = s;
}

// ---------------- launch ----------------

extern "C" void kernel_launch(void* const* d_in, const int* in_sizes, int n_in,
                              void* d_out, int out_size, void* d_ws, size_t ws_size,
                              hipStream_t stream) {
  const float* query  = (const float*)d_in[0];
  const float* keys   = (const float*)d_in[1];
  const float* values = (const float*)d_in[2];
  const float* mask   = (const float*)d_in[3];
  const float* W1     = (const float*)d_in[4];
  const float* b1     = (const float*)d_in[5];
  const float* W2     = (const float*)d_in[6];
  const float* b2     = (const float*)d_in[7];
  const float* wscore = (const float*)d_in[8];
  const float* bscore = (const float*)d_in[9];
  float* out = (float*)d_out;

  char* ws = (char*)d_ws;
  short* keysb = (short*)(ws);                   // 33,554,432 B
  short* wktf  = (short*)(ws + 33554432ull);     // 33,554,432 B (frag order, per batch)
  short* w2f   = (short*)(ws + 67108864ull);     //  2,097,152 B (frag order)
  float* biasb = (float*)(ws + 69206016ull);     //    262,144 B
  short* h1    = (short*)(ws + 69468160ull);     // 134,217,728 B
  float* spart = (float*)(ws + 203685888ull);    //  4,194,304 B
  float* part  = (float*)(ws + 207880192ull);    //  2,097,152 B (total ~210 MB)

  k_prep_all<<<8704, 256, 0, stream>>>(keys, W2, W1, query, b1,
                                       keysb, w2f, wktf, biasb);

  k_gemm<1><<<2048, 512, 0, stream>>>(keysb, wktf, biasb, nullptr, h1, nullptr);
  k_gemm<2><<<2048, 512, 0, stream>>>(h1, w2f, b2, wscore, nullptr, spart);

  k_out<<<512, 256, 0, stream>>>(spart, mask, bscore, values, part);
  k_red<<<64, 256, 0, stream>>>(part, out);
}

// Round 20
// 253.312 us; speedup vs baseline: 1.0722x; 1.0722x over previous
//
#include <hip/hip_runtime.h>

#define DEV __device__ __forceinline__

typedef __attribute__((ext_vector_type(4))) float f32x4;
typedef __attribute__((ext_vector_type(8))) short short8;
typedef __attribute__((ext_vector_type(4))) short s16x4;
typedef __attribute__((ext_vector_type(4))) float f32x4v;

DEV short f2bf(float f) {
  union { float f; unsigned u; } v; v.f = f;
  unsigned r = (v.u + 0x7FFFu + ((v.u >> 16) & 1u)) >> 16;
  return (short)r;
}

DEV void gload16(const void* g, void* l) {
  __builtin_amdgcn_global_load_lds(
      (const __attribute__((address_space(1))) void*)g,
      (__attribute__((address_space(3))) void*)l, 16, 0, 0);
}

#define BAR() __builtin_amdgcn_s_barrier()
#define LGKMW(n)                                              \
  {                                                           \
    asm volatile("s_waitcnt lgkmcnt(" #n ")" ::: "memory");   \
    __builtin_amdgcn_sched_barrier(0);                        \
  }
#define VMW(n)                                                \
  {                                                           \
    asm volatile("s_waitcnt vmcnt(" #n ")" ::: "memory");     \
    __builtin_amdgcn_sched_barrier(0);                        \
  }

// ---------------- merged prep kernel ----------------
// Role-partitioned single launch (overlaps the three preps' memory traffic):
//   blocks [0,256):    wkt4  (r = bid:      bg = r&15, d0g = r>>4)
//   blocks [256,512):  w2f   (r = bid-256:  kt = r&15, n0g = r>>4)
//   blocks [512,8704): keys  (r = bid-512:  flat convert)

__global__ __launch_bounds__(256) void k_prep_all(
    const float* __restrict__ keys, const float* __restrict__ w2,
    const float* __restrict__ w1, const float* __restrict__ query,
    const float* __restrict__ b1, short* __restrict__ keysb,
    short* __restrict__ w2f, short* __restrict__ wktf,
    float* __restrict__ biasb) {
  __shared__ __align__(16) char smem[45056];
  const int bid = blockIdx.x;
  const int tid = threadIdx.x;

  if (bid < 256) {
    // ---- wkt4 role: 4-batch-sharing Wk prep + fused bias ----
    short (*tile)[64][72] = (short (*)[64][72])(smem);
    float (*qlds)[256] = (float (*)[256])(smem + 36864);
    float (*redm)[64][4] = (float (*)[64][4])(smem + 40960);
    const int r = bid;
    const int bg = r & 15, d0g = r >> 4, d0 = d0g * 64;
    const int d = tid & 63, mq = tid >> 6;

    for (int idx = tid; idx < 1024; idx += 256)
      qlds[idx >> 8][idx & 255] = query[(bg * 4 + (idx >> 8)) * 256 + (idx & 255)];
    __syncthreads();

    float bacc[4] = {0.f, 0.f, 0.f, 0.f};
    const int l = tid & 63, cgl = tid >> 6;

    for (int mc = 0; mc < 4; ++mc) {
#pragma unroll 4
      for (int i = 0; i < 16; ++i) {
        int ml = i * 4 + mq;
        int m = mc * 64 + ml;
        float wa = w1[(size_t)m * 1024 + d0 + d];
        float wb = w1[(size_t)(256 + m) * 1024 + d0 + d];
        float wc = w1[(size_t)(512 + m) * 1024 + d0 + d];
        float wd = w1[(size_t)(768 + m) * 1024 + d0 + d];
        float bc = wb - wc, ac = wa + wc;
#pragma unroll
        for (int bb = 0; bb < 4; ++bb) {
          float qv = qlds[bb][m];
          tile[bb][d][ml] = f2bf(bc + qv * wd);
          bacc[bb] += qv * ac;
        }
      }
      __syncthreads();
#pragma unroll
      for (int bb = 0; bb < 4; ++bb) {
        short* ob = wktf + (size_t)(bg * 4 + bb) * 262144;
#pragma unroll
        for (int kh = 0; kh < 2; ++kh) {
          short8 v = *(const short8*)&tile[bb][cgl * 16 + (l & 15)]
                                          [kh * 32 + (l >> 4) * 8];
          *(short8*)&ob[((size_t)((mc * 2 + kh) * 64 + d0g * 4 + cgl)) * 512 + l * 8] = v;
        }
      }
      __syncthreads();
    }

    redm[0][d][mq] = bacc[0];
    redm[1][d][mq] = bacc[1];
    redm[2][d][mq] = bacc[2];
    redm[3][d][mq] = bacc[3];
    __syncthreads();
    const int bb = tid >> 6, dd = tid & 63;
    biasb[(bg * 4 + bb) * 1024 + d0 + dd] =
        redm[bb][dd][0] + redm[bb][dd][1] + redm[bb][dd][2] + redm[bb][dd][3] +
        b1[d0 + dd];
  } else if (bid < 512) {
    // ---- w2f role: W2 -> 16x16x32 fragment records ----
    float (*tile)[65] = (float (*)[65])(smem);
    const int r = bid - 256;
    const int kt = r & 15, n0 = (r >> 4) * 64;
    const int a = tid & 63, q = tid >> 6;
#pragma unroll
    for (int i = 0; i < 16; ++i) {
      int kk = i * 4 + q;
      tile[kk][a] = w2[(size_t)(kt * 64 + kk) * 1024 + n0 + a];
    }
    __syncthreads();
    const int l = tid & 63, cgl = tid >> 6;
#pragma unroll
    for (int kh = 0; kh < 2; ++kh) {
      short8 v;
#pragma unroll
      for (int j = 0; j < 8; ++j)
        v[j] = f2bf(tile[kh * 32 + (l >> 4) * 8 + j][cgl * 16 + (l & 15)]);
      *(short8*)&w2f[((size_t)((kt * 2 + kh) * 64 + (n0 >> 4) + cgl)) * 512 + l * 8] = v;
    }
  } else {
    // ---- keys role: f32 -> bf16 convert, 8 elems/thread ----
    int i = ((bid - 512) * 256 + tid) * 8;
    f32x4v v0 = *(const f32x4v*)(keys + i);
    f32x4v v1 = *(const f32x4v*)(keys + i + 4);
    short8 s;
    s[0] = f2bf(v0[0]); s[1] = f2bf(v0[1]); s[2] = f2bf(v0[2]); s[3] = f2bf(v0[3]);
    s[4] = f2bf(v1[0]); s[5] = f2bf(v1[1]); s[6] = f2bf(v1[2]); s[7] = f2bf(v1[3]);
    *(short8*)(keysb + i) = s;
  }
}

// ---------------- A-in-LDS / B-from-global GEMM (TN), 16x16x32 -------------
// BM=128, BN=256, BK=64, 256 thr (4 waves, wave tile 128x64), launch_bounds(256,2)
// -> 2 blocks/CU. LDS: 4 x 16KB A-buffers only (B straight from L2 in fragment
// order, double-banked 2 tiles ahead). One barrier + 64 MFMA per K64,
// counted VMW(12) (12 = A 4 + B 8 ops per tile-group; 2 groups in flight).
// MODE 1: per-batch keys@Wk + bias, relu -> h1 (bf16).  K=256 (KT=4).
// MODE 2: h1@w2f + b2, relu, dot w_score -> score partials. K=1024 (KT=16).

template <int MODE>
__global__ __launch_bounds__(256, 2) void k_gemm(const short* __restrict__ A,
                                                 const short* __restrict__ Bf,
                                                 const float* __restrict__ bias,
                                                 const float* __restrict__ wscore,
                                                 short* __restrict__ hout,
                                                 float* __restrict__ spart) {
  __shared__ short lds[32768];  // 4 bufs x 8192 shorts (16KB each)
  constexpr int SK = (MODE == 1) ? 256 : 1024;
  constexpr int KT = (MODE == 1) ? 4 : 16;

  const int tid = threadIdx.x;
  const int bx = blockIdx.x;
  const int L = (bx & 7) * 256 + (bx >> 3);  // XCD swizzle

  const short *Ab, *Bb;
  const float *biasp, *wsp = nullptr;
  short* houtp = nullptr;
  int rt, ct;
  if constexpr (MODE == 1) {
    const int b = L >> 5;
    rt = (L >> 2) & 7; ct = L & 3;
    Ab = A + ((size_t)(b * 1024 + rt * 128)) * 256;
    Bb = Bf + (size_t)b * 262144;
    biasp = bias + b * 1024 + ct * 256;
    houtp = hout + ((size_t)(b * 1024 + rt * 128)) * 1024 + ct * 256;
  } else {
    rt = L >> 2; ct = L & 3;
    Ab = A + (size_t)rt * 128 * 1024;
    Bb = Bf;
    biasp = bias + ct * 256;
    wsp = wscore + ct * 256;
  }

  // A staging: chunk s -> row = s>>3, slot = s&7, src k-chunk = slot^(row&7)
  int gA[4], dA[4];
#pragma unroll
  for (int j = 0; j < 4; ++j) {
    int s = tid + j * 256, row = s >> 3, kc = (s & 7) ^ (row & 7);
    gA[j] = row * SK + kc * 8;
    dA[j] = s * 8;
  }
  auto STAGE = [&](int kt) {
    const int bb = (kt & 3) * 8192;
#pragma unroll
    for (int j = 0; j < 4; ++j) gload16(Ab + gA[j] + kt * 64, &lds[bb + dA[j]]);
  };

  const int lane = tid & 63, l15 = lane & 15, l4 = lane >> 4, wc = tid >> 6;
  // af read: row = m*16 + l15; chunk kh*4+l4 stored at slot^(l15&7)
  const int afo0 = l15 * 64 + ((l4 ^ (l15 & 7)) * 8);
  const int afo1 = l15 * 64 + (((4 + l4) ^ (l15 & 7)) * 8);

  f32x4 acc[8][4];
#pragma unroll
  for (int m = 0; m < 8; ++m)
#pragma unroll
    for (int n = 0; n < 4; ++n) acc[m][n] = f32x4{0.f, 0.f, 0.f, 0.f};
  short8 bf[2][4][2];  // [bank][n][kh]
  short8 af[8];

#define LOADB(kt, BK_)                                                          \
  _Pragma("unroll") for (int n_ = 0; n_ < 4; ++n_) {                            \
    _Pragma("unroll") for (int kh_ = 0; kh_ < 2; ++kh_) {                       \
      bf[BK_][n_][kh_] = *(const short8*)(Bb +                                  \
          ((size_t)(((kt) * 2 + kh_) * 64 + ct * 16 + n_ * 4 + wc) << 9) +      \
          lane * 8);                                                            \
    }                                                                           \
  }

  // prologue: 2 tile-groups in flight (each = A 4 ops + B 8 ops)
  STAGE(0); LOADB(0, 0);
  STAGE(1); LOADB(1, 1);
  VMW(12);
  BAR();

#pragma unroll
  for (int t = 0; t < KT; ++t) {
    const int bb = (t & 3) * 8192;
    // kh0
#pragma unroll
    for (int m = 0; m < 8; ++m) af[m] = *(const short8*)&lds[bb + afo0 + m * 1024];
    LGKMW(0);
    __builtin_amdgcn_s_setprio(1);
#pragma unroll
    for (int m = 0; m < 8; ++m)
#pragma unroll
      for (int n = 0; n < 4; ++n)
        acc[m][n] = __builtin_amdgcn_mfma_f32_16x16x32_bf16(bf[t & 1][n][0], af[m],
                                                            acc[m][n], 0, 0, 0);
    __builtin_amdgcn_s_setprio(0);
    // kh1
#pragma unroll
    for (int m = 0; m < 8; ++m) af[m] = *(const short8*)&lds[bb + afo1 + m * 1024];
    if (t + 2 < KT) STAGE(t + 2);
    LGKMW(0);
    __builtin_amdgcn_s_setprio(1);
#pragma unroll
    for (int m = 0; m < 8; ++m)
#pragma unroll
      for (int n = 0; n < 4; ++n)
        acc[m][n] = __builtin_amdgcn_mfma_f32_16x16x32_bf16(bf[t & 1][n][1], af[m],
                                                            acc[m][n], 0, 0, 0);
    __builtin_amdgcn_s_setprio(0);
    if (t + 2 < KT) {
      LOADB(t + 2, (t & 1));
      VMW(12);       // drains group t+1 (A in LDS + B in regs), keeps t+2 in flight
    } else {
      VMW(0);        // tail: drain final group
    }
    BAR();
  }
#undef LOADB

  // ---------------- epilogue ----------------
  // C fragments: row = m*16 + l15, col(n,r2) = n*64 + wc*16 + l4*4 + r2
  if constexpr (MODE == 1) {
    float bv[4][4];
#pragma unroll
    for (int n = 0; n < 4; ++n)
#pragma unroll
      for (int r2 = 0; r2 < 4; ++r2)
        bv[n][r2] = biasp[n * 64 + wc * 16 + l4 * 4 + r2];
#pragma unroll
    for (int m = 0; m < 8; ++m) {
      int row = m * 16 + l15;
#pragma unroll
      for (int n = 0; n < 4; ++n) {
        s16x4 pk;
#pragma unroll
        for (int r2 = 0; r2 < 4; ++r2)
          pk[r2] = f2bf(fmaxf(acc[m][n][r2] + bv[n][r2], 0.f));
        *(s16x4*)&houtp[(size_t)row * 1024 + n * 64 + wc * 16 + l4 * 4] = pk;
      }
    }
  } else {
    float bv[4][4], wv[4][4];
#pragma unroll
    for (int n = 0; n < 4; ++n)
#pragma unroll
      for (int r2 = 0; r2 < 4; ++r2) {
        int c = n * 64 + wc * 16 + l4 * 4 + r2;
        bv[n][r2] = biasp[c];
        wv[n][r2] = wsp[c];
      }
    float* so = spart + ((size_t)(ct * 4 + wc) << 16) + rt * 128;
#pragma unroll
    for (int m = 0; m < 8; ++m) {
      float s = 0.f;
#pragma unroll
      for (int n = 0; n < 4; ++n)
#pragma unroll
        for (int r2 = 0; r2 < 4; ++r2)
          s += fmaxf(acc[m][n][r2] + bv[n][r2], 0.f) * wv[n][r2];
      s += __shfl_xor(s, 16);
      s += __shfl_xor(s, 32);
      if (lane < 16) so[m * 16 + l15] = s;
    }
  }
}

// ---------------- fused softmax + output partials ----------------
// Block (b, ts): recompute the full-row softmax from spart (identical FP order
// in every sibling block -> deterministic), then partial-PV over
// t in [ts*128, ts*128+128) for all 1024 d (float4/thread).
__global__ __launch_bounds__(256) void k_out(const float* __restrict__ spart,
                                             const float* __restrict__ mask,
                                             const float* __restrict__ bscore,
                                             const float* __restrict__ values,
                                             float* __restrict__ part) {
  const int b = blockIdx.x >> 3, ts = blockIdx.x & 7;
  const int tid = threadIdx.x;
  __shared__ float sm[1024];
  __shared__ float red[8];
  const float bs = bscore[0];
  float lmax = -3.0e38f;
  for (int t = tid; t < 1024; t += 256) {
    float s = bs;
#pragma unroll
    for (int c = 0; c < 16; ++c) s += spart[(size_t)c * 65536 + b * 1024 + t];
    float lg = s + mask[b * 1024 + t] * (-1e9f);
    sm[t] = lg;
    lmax = fmaxf(lmax, lg);
  }
  for (int o = 32; o; o >>= 1) lmax = fmaxf(lmax, __shfl_xor(lmax, o));
  const int wid = tid >> 6, lane = tid & 63;
  if (lane == 0) red[wid] = lmax;
  __syncthreads();
  float bmax = fmaxf(fmaxf(red[0], red[1]), fmaxf(red[2], red[3]));
  float lsum = 0.f;
  for (int t = tid; t < 1024; t += 256) {
    float e = __expf(sm[t] - bmax);
    sm[t] = e;
    lsum += e;
  }
  for (int o = 32; o; o >>= 1) lsum += __shfl_xor(lsum, o);
  __syncthreads();
  if (lane == 0) red[wid] = lsum;
  __syncthreads();
  const float inv = 1.0f / (red[0] + red[1] + red[2] + red[3]);

  const float* vb = values + ((size_t)b * 1024 + ts * 128) * 1024 + tid * 4;
  f32x4 acc = {0.f, 0.f, 0.f, 0.f};
#pragma unroll 8
  for (int t = 0; t < 128; ++t) {
    f32x4v v = *(const f32x4v*)(vb + (size_t)t * 1024);
    float a = sm[ts * 128 + t] * inv;
    acc[0] += a * v[0]; acc[1] += a * v[1]; acc[2] += a * v[2]; acc[3] += a * v[3];
  }
  *(f32x4*)(part + ((size_t)(b * 8 + ts)) * 1024 + tid * 4) = acc;
}

__global__ __launch_bounds__(256) void k_red(const float* __restrict__ part,
                                             float* __restrict__ out) {
  const int b = blockIdx.x;
  const int c4 = threadIdx.x * 4;
  f32x4 s = {0.f, 0.f, 0.f, 0.f};
#pragma unroll
  for (int ts = 0; ts < 8; ++ts) {
    f32x4v v = *(const f32x4v*)(part + ((size_t)(b * 8 + ts)) * 1024 + c4);
    s[0] += v[0]; s[1] += v[1]; s[2] += v[2]; s[3] += v[3];
  }
  *(f32x4*)(out + b * 1024 + c4) = s;
}

// ---------------- launch ----------------

extern "C" void kernel_launch(void* const* d_in, const int* in_sizes, int n_in,
                              void* d_out, int out_size, void* d_ws, size_t ws_size,
                              hipStream_t stream) {
  const float* query  = (const float*)d_in[0];
  const float* keys   = (const float*)d_in[1];
  const float* values = (const float*)d_in[2];
  const float* mask   = (const float*)d_in[3];
  const float* W1     = (const float*)d_in[4];
  const float* b1     = (const float*)d_in[5];
  const float* W2     = (const float*)d_in[6];
  const float* b2     = (const float*)d_in[7];
  const float* wscore = (const float*)d_in[8];
  const float* bscore = (const float*)d_in[9];
  float* out = (float*)d_out;

  char* ws = (char*)d_ws;
  short* keysb = (short*)(ws);                   // 33,554,432 B
  short* wktf  = (short*)(ws + 33554432ull);     // 33,554,432 B (frag order, per batch)
  short* w2f   = (short*)(ws + 67108864ull);     //  2,097,152 B (frag order)
  float* biasb = (float*)(ws + 69206016ull);     //    262,144 B
  short* h1    = (short*)(ws + 69468160ull);     // 134,217,728 B
  float* spart = (float*)(ws + 203685888ull);    //  4,194,304 B
  float* part  = (float*)(ws + 207880192ull);    //  2,097,152 B (total ~210 MB)

  k_prep_all<<<8704, 256, 0, stream>>>(keys, W2, W1, query, b1,
                                       keysb, w2f, wktf, biasb);

  k_gemm<1><<<2048, 256, 0, stream>>>(keysb, wktf, biasb, nullptr, h1, nullptr);
  k_gemm<2><<<2048, 256, 0, stream>>>(h1, w2f, b2, wscore, nullptr, spart);

  k_out<<<512, 256, 0, stream>>>(spart, mask, bscore, values, part);
  k_red<<<64, 256, 0, stream>>>(part, out);
}